// Round 12
// baseline (316.744 us; speedup 1.0000x reference)
//
#include <hip/hip_runtime.h>

#define NN 50000
#define NE 800000
#define IND 768
#define CH  128    // output channels per node for both layers
#define NBLK 196   // ceil(NN/256)
#define GBM 64
#define GBK 32
#define MBLKS 782  // ceil(NN/GBM)

typedef __attribute__((ext_vector_type(8))) short bf16x8;
typedef __attribute__((ext_vector_type(4))) float f32x4;

// ---------------- bf16 split helpers ----------------
__device__ __forceinline__ unsigned short bf16_rne(float f) {
    unsigned u = __float_as_uint(f);
    u += 0x7fffu + ((u >> 16) & 1u);
    return (unsigned short)(u >> 16);
}
__device__ __forceinline__ float bf16_to_f(unsigned short b) {
    return __uint_as_float(((unsigned)b) << 16);
}

// ---------------- prep: W -> K-tiled, 8-way-swizzled bf16 hi/lo planes ----------------
// Per plane: [K/32 tiles][4096 ushorts]. Granule j of row n stored at
// g = n*4 + (j ^ ((n>>1)&3)); measured 0 LDS bank conflicts (round 7/8/11 PMC).
__global__ void prep_b1(const float* __restrict__ W1,
                        unsigned short* __restrict__ Bhi, unsigned short* __restrict__ Blo)
{
    int idx = blockIdx.x * blockDim.x + threadIdx.x;   // n*IND + k
    if (idx >= CH * IND) return;
    int n = idx / IND, k = idx % IND;
    float v = W1[(size_t)(n >> 5) * IND * 32 + (size_t)k * 32 + (n & 31)];
    int kt = k >> 5, kk = k & 31, j = kk >> 3, e = kk & 7;
    int g = n * 4 + (j ^ ((n >> 1) & 3));
    int off = kt * 4096 + g * 8 + e;
    unsigned short hi = bf16_rne(v);
    float lo = v - bf16_to_f(hi);
    Bhi[off] = hi;
    Blo[off] = bf16_rne(lo);
}

__global__ void prep_b2(const float* __restrict__ W2,
                        unsigned short* __restrict__ Bhi, unsigned short* __restrict__ Blo)
{
    int idx = blockIdx.x * blockDim.x + threadIdx.x;   // n*CH + k
    if (idx >= CH * CH) return;
    int n = idx / CH, k = idx % CH;
    float v = W2[(size_t)k * CH + n];
    int kt = k >> 5, kk = k & 31, j = kk >> 3, e = kk & 7;
    int g = n * 4 + (j ^ ((n >> 1) & 3));
    int off = kt * 4096 + g * 8 + e;
    unsigned short hi = bf16_rne(v);
    float lo = v - bf16_to_f(hi);
    Bhi[off] = hi;
    Blo[off] = bf16_rne(lo);
}

// ---------------- GEMM (split-K): counted-vmcnt depth-2 pipeline, 32KB LDS ----------------
// Block 256 thr = 4 waves (2x2), wave tile 32x64. A in 2 named register sets (2-deep),
// B via global_load_lds into 2 buffers. 8 VMEM/wave/tile -> static vmcnt(8). Raw barriers.
__device__ __forceinline__ void cvt_split(const float4& u0, const float4& u1,
                                          bf16x8& ahi, bf16x8& alo)
{
    float f[8] = {u0.x, u0.y, u0.z, u0.w, u1.x, u1.y, u1.z, u1.w};
    unsigned short hi[8], lo[8];
    #pragma unroll
    for (int q = 0; q < 8; ++q) {
        hi[q] = bf16_rne(f[q]);
        lo[q] = bf16_rne(f[q] - bf16_to_f(hi[q]));
    }
    ahi = *(const bf16x8*)hi;
    alo = *(const bf16x8*)lo;
}

// issue tile kt (local): A set (4 float4 regular loads) + 4 B-DMA chunks into bbuf
__device__ __forceinline__ void issue_tile(
    int kt, const float* ap0, const float* ap1,
    float4& x00, float4& x01, float4& x10, float4& x11,
    const unsigned short* __restrict__ Bthi, const unsigned short* __restrict__ Btlo,
    unsigned short* bbuf, int kt0, int w, int lane)
{
    const float* p0 = ap0 + (size_t)kt * GBK;
    const float* p1 = ap1 + (size_t)kt * GBK;
    x00 = *(const float4*)p0;  x01 = *(const float4*)(p0 + 4);
    x10 = *(const float4*)p1;  x11 = *(const float4*)(p1 + 4);
    #pragma unroll
    for (int i = 0; i < 4; ++i) {
        const int c = w * 4 + i;               // 0..15
        const int plane = c >> 3;
        const int co = (c & 7) * 512;          // ushort offset in 8KB plane
        const unsigned short* gs =
            (plane ? Btlo : Bthi) + (size_t)(kt0 + kt) * 4096 + co + lane * 8;
        __builtin_amdgcn_global_load_lds(
            (const __attribute__((address_space(1))) unsigned int*)gs,
            (__attribute__((address_space(3))) unsigned int*)(bbuf + plane * 4096 + co),
            16, 0, 0);
    }
}

__device__ __forceinline__ void mfma_tile(
    const bf16x8& a0h, const bf16x8& a0l, const bf16x8& a1h, const bf16x8& a1l,
    const unsigned short* cbuf, const int* boff, f32x4 (*acc)[4])
{
    #pragma unroll
    for (int ni = 0; ni < 4; ++ni) {
        const bf16x8 bhi = *(const bf16x8*)(cbuf + boff[ni]);
        const bf16x8 blo = *(const bf16x8*)(cbuf + 4096 + boff[ni]);
        acc[0][ni] = __builtin_amdgcn_mfma_f32_16x16x32_bf16(a0h, bhi, acc[0][ni], 0, 0, 0);
        acc[0][ni] = __builtin_amdgcn_mfma_f32_16x16x32_bf16(a0h, blo, acc[0][ni], 0, 0, 0);
        acc[0][ni] = __builtin_amdgcn_mfma_f32_16x16x32_bf16(a0l, bhi, acc[0][ni], 0, 0, 0);
        acc[1][ni] = __builtin_amdgcn_mfma_f32_16x16x32_bf16(a1h, bhi, acc[1][ni], 0, 0, 0);
        acc[1][ni] = __builtin_amdgcn_mfma_f32_16x16x32_bf16(a1h, blo, acc[1][ni], 0, 0, 0);
        acc[1][ni] = __builtin_amdgcn_mfma_f32_16x16x32_bf16(a1l, bhi, acc[1][ni], 0, 0, 0);
    }
}

// one step: wait own tile's 8 VMEM -> barrier -> cvt A -> MFMA -> barrier -> issue kt+2
#define GEMM_STEP(KT, BUF, X00, X01, X10, X11, DO_ISSUE, WAITN) do {               \
    __builtin_amdgcn_sched_barrier(0);                                             \
    asm volatile("s_waitcnt vmcnt(" #WAITN ")" ::: "memory");                      \
    __builtin_amdgcn_sched_barrier(0);                                             \
    __builtin_amdgcn_s_barrier();                                                  \
    __builtin_amdgcn_sched_barrier(0);                                             \
    bf16x8 a0h_, a0l_, a1h_, a1l_;                                                 \
    cvt_split(X00, X01, a0h_, a0l_);                                               \
    cvt_split(X10, X11, a1h_, a1l_);                                               \
    mfma_tile(a0h_, a0l_, a1h_, a1l_, &Bs[BUF][0][0], boff, acc);                  \
    __builtin_amdgcn_s_barrier();                                                  \
    __builtin_amdgcn_sched_barrier(0);                                             \
    if (DO_ISSUE)                                                                  \
        issue_tile((KT) + 2, ap0, ap1, X00, X01, X10, X11,                         \
                   Bthi, Btlo, &Bs[BUF][0][0], kt0, w, lane);                      \
} while (0)

__global__ __launch_bounds__(256) void gemm_ks(
    const float* __restrict__ A,
    const unsigned short* __restrict__ Bthi, const unsigned short* __restrict__ Btlo,
    float* __restrict__ P, int K, int KS)
{
    __shared__ unsigned short Bs[2][2][4096];   // 2 bufs x (hi,lo) x 8KB = 32KB

    const int t = threadIdx.x;
    const int lane = t & 63;
    const int w = t >> 6;
    const int wr = w >> 1, wc = w & 1;
    const int lrow = lane & 15, kg = lane >> 4;

    const int mb = blockIdx.x % MBLKS;
    const int ks = blockIdx.x / MBLKS;
    const int klen = K / KS;
    const int kt0 = (ks * klen) >> 5;
    const int nt = klen >> 5;                   // 12 (L1) or 4 (L2); even, >=4
    const int m0 = mb * GBM;

    // A fragment pointers (row-clamped; loads always execute -> uniform vmem count)
    const int r0 = m0 + wr * 32 + lrow;
    const int r1 = r0 + 16;
    const bool v0 = (m0 + wr * 32) < NN;
    const bool v1 = (m0 + wr * 32 + 16) < NN;
    const float* ap0 = A + (size_t)(v0 ? r0 : 0) * K + ks * klen + kg * 8;
    const float* ap1 = A + (size_t)(v1 ? r1 : 0) * K + ks * klen + kg * 8;

    int boff[4];
    #pragma unroll
    for (int ni = 0; ni < 4; ++ni) {
        const int n = wc * 64 + ni * 16 + lrow;
        boff[ni] = (n * 4 + (kg ^ ((n >> 1) & 3))) * 8;
    }

    f32x4 acc[2][4];
    #pragma unroll
    for (int i = 0; i < 2; ++i)
        #pragma unroll
        for (int j = 0; j < 4; ++j) acc[i][j] = (f32x4)(0.f);

    // ---- prologue: tiles 0,1 -> reg sets + bufs (16 VMEM outstanding/wave) ----
    float4 a000, a001, a010, a011;   // set 0 (even tiles)
    float4 a100, a101, a110, a111;   // set 1 (odd tiles)
    issue_tile(0, ap0, ap1, a000, a001, a010, a011, Bthi, Btlo, &Bs[0][0][0], kt0, w, lane);
    issue_tile(1, ap0, ap1, a100, a101, a110, a111, Bthi, Btlo, &Bs[1][0][0], kt0, w, lane);

    // ---- main loop: kt = 0 .. nt-3 (nt-2 iters, even), issue kt+2, wait vmcnt(8) ----
    for (int kt2 = 0; kt2 < nt - 2; kt2 += 2) {
        GEMM_STEP(kt2,     0, a000, a001, a010, a011, true, 8);
        GEMM_STEP(kt2 + 1, 1, a100, a101, a110, a111, true, 8);
    }
    // ---- peeled tail ----
    GEMM_STEP(nt - 2, 0, a000, a001, a010, a011, false, 8);
    GEMM_STEP(nt - 1, 1, a100, a101, a110, a111, false, 0);

    // ---- partial write: col = lane&15, row = kg*4 + j ----
    float* Pks = P + (size_t)ks * NN * CH;
    #pragma unroll
    for (int mi = 0; mi < 2; ++mi) {
        const bool mv = mi ? v1 : v0;
        if (mv) {
            const int rbase = m0 + wr * 32 + mi * 16 + kg * 4;
            #pragma unroll
            for (int ni = 0; ni < 4; ++ni) {
                const int col = wc * 64 + ni * 16 + lrow;
                const f32x4 a = acc[mi][ni];
                #pragma unroll
                for (int j = 0; j < 4; ++j) {
                    const int r = rbase + j;
                    if (r < NN) Pks[(size_t)r * CH + col] = a[j];
                }
            }
        }
    }
}

// ---------------- reduce partials + compute s_src/s_dst + emit z16 ----------------
template<int H, int KS>
__global__ __launch_bounds__(256) void reduce_s(
    const float* __restrict__ P, const float* __restrict__ a,
    unsigned short* __restrict__ z16, float* __restrict__ ss, float* __restrict__ sd)
{
    const int wid = threadIdx.x >> 6;
    const int lane = threadIdx.x & 63;
    const int n = blockIdx.x * 4 + wid;
    if (n >= NN) return;
    const int c0 = lane * 2;
    float2 v = *(const float2*)&P[(size_t)n * CH + c0];
    if (KS == 2) {
        const float2 v1 = *(const float2*)&P[(size_t)(NN + n) * CH + c0];
        v.x += v1.x; v.y += v1.y;
    }
    ushort2 u;
    u.x = bf16_rne(v.x);
    u.y = bf16_rne(v.y);
    *(ushort2*)&z16[(size_t)n * CH + c0] = u;

    const int D = CH / H;
    const int head = c0 / D;
    const int d0 = c0 % D;
    float ps = v.x * a[head * 2 * D + d0]     + v.y * a[head * 2 * D + d0 + 1];
    float pd = v.x * a[head * 2 * D + D + d0] + v.y * a[head * 2 * D + D + d0 + 1];
    #pragma unroll
    for (int off = 1; off < D / 2; off <<= 1) {
        ps += __shfl_xor(ps, off, 64);
        pd += __shfl_xor(pd, off, 64);
    }
    if ((lane % (D / 2)) == 0) {
        ss[n * H + head] = ps;
        sd[n * H + head] = pd;
    }
}

// ---------------- CSR build ----------------
__global__ __launch_bounds__(256) void zero_cc(int* __restrict__ counts, int* __restrict__ cursor)
{
    int i = blockIdx.x * 256 + threadIdx.x;
    if (i < NN) { counts[i] = 0; cursor[i] = 0; }
}

__global__ void count_k(const int* __restrict__ dst, int* __restrict__ counts)
{
    int e = blockIdx.x * blockDim.x + threadIdx.x;
    if (e < NE) atomicAdd(&counts[dst[e]], 1);
}

__global__ __launch_bounds__(256) void scan1(const int* __restrict__ counts,
                                             int* __restrict__ exc, int* __restrict__ bsum)
{
    __shared__ int s[256];
    const int t = threadIdx.x;
    const int i = blockIdx.x * 256 + t;
    const int val = (i < NN) ? counts[i] : 0;
    s[t] = val;
    __syncthreads();
    #pragma unroll
    for (int off = 1; off < 256; off <<= 1) {
        int v = (t >= off) ? s[t - off] : 0;
        __syncthreads();
        s[t] += v;
        __syncthreads();
    }
    if (i < NN) exc[i] = s[t] - val;
    if (t == 255) bsum[blockIdx.x] = s[255];
}

__global__ __launch_bounds__(256) void scan2(const int* __restrict__ bsum,
                                             int* __restrict__ bexc)
{
    __shared__ int s[256];
    const int t = threadIdx.x;
    const int val = (t < NBLK) ? bsum[t] : 0;
    s[t] = val;
    __syncthreads();
    #pragma unroll
    for (int off = 1; off < 256; off <<= 1) {
        int v = (t >= off) ? s[t - off] : 0;
        __syncthreads();
        s[t] += v;
        __syncthreads();
    }
    bexc[t] = s[t] - val;
}

__global__ __launch_bounds__(256) void scan3(const int* __restrict__ exc,
                                             const int* __restrict__ bexc,
                                             int* __restrict__ offsets)
{
    const int i = blockIdx.x * 256 + threadIdx.x;
    if (i < NN) offsets[i] = exc[i] + bexc[i >> 8];
    if (i == 0) offsets[NN] = NE;
}

// scatter permuted SOURCE ids directly: es[p] = src[e]
__global__ void scatter_es(const int* __restrict__ src, const int* __restrict__ dst,
                           const int* __restrict__ offsets, int* __restrict__ cursor,
                           int* __restrict__ es)
{
    int e = blockIdx.x * blockDim.x + threadIdx.x;
    if (e >= NE) return;
    int d = dst[e];
    int p = offsets[d] + atomicAdd(&cursor[d], 1);
    es[p] = src[e];
}

// ---------------- fused softmax + aggregation: one WAVE per dst node ----------------
template<int H, bool ELU>
__global__ __launch_bounds__(256) void fused_agg(
    const int* __restrict__ offsets, const int* __restrict__ es,
    const float* __restrict__ s_src, const float* __restrict__ s_dst,
    const unsigned short* __restrict__ z16, float* __restrict__ out)
{
    const int wid = threadIdx.x >> 6;
    const int lane = threadIdx.x & 63;
    const int n = blockIdx.x * 4 + wid;     // NN % 4 == 0, exact
    const int beg = offsets[n], end = offsets[n + 1];
    const int deg = end - beg;

    __shared__ float alpha_sh[4][128][H];
    __shared__ int   es_sh[4][128];
    __shared__ int   maxdeg;
    if (threadIdx.x == 0) maxdeg = 0;
    __syncthreads();
    if (lane == 0) atomicMax(&maxdeg, deg);
    __syncthreads();
    const int nch = (maxdeg + 127) >> 7;    // uniform across block -> safe barriers

    float sdv[H];
    #pragma unroll
    for (int h = 0; h < H; ++h) sdv[h] = s_dst[(size_t)n * H + h];

    // ---- pass 1: per-head max ----
    float m[H];
    #pragma unroll
    for (int h = 0; h < H; ++h) m[h] = -INFINITY;
    for (int i = beg + lane; i < end; i += 64) {
        const int s = es[i];
        if (H == 4) {
            const float4 sv = *(const float4*)&s_src[(size_t)s * 4];
            const float svv[4] = {sv.x, sv.y, sv.z, sv.w};
            #pragma unroll
            for (int h = 0; h < 4; ++h) {
                float v = svv[h] + sdv[h];
                v = v > 0.f ? v : 0.01f * v;
                m[h] = fmaxf(m[h], v);
            }
        } else {
            float v = s_src[s] + sdv[0];
            v = v > 0.f ? v : 0.01f * v;
            m[0] = fmaxf(m[0], v);
        }
    }
    #pragma unroll
    for (int h = 0; h < H; ++h)
        #pragma unroll
        for (int off = 1; off < 64; off <<= 1)
            m[h] = fmaxf(m[h], __shfl_xor(m[h], off, 64));

    // ---- pass 2: per-head sum of exp ----
    float ssum[H];
    #pragma unroll
    for (int h = 0; h < H; ++h) ssum[h] = 0.f;
    for (int i = beg + lane; i < end; i += 64) {
        const int s = es[i];
        if (H == 4) {
            const float4 sv = *(const float4*)&s_src[(size_t)s * 4];
            const float svv[4] = {sv.x, sv.y, sv.z, sv.w};
            #pragma unroll
            for (int h = 0; h < 4; ++h) {
                float v = svv[h] + sdv[h];
                v = v > 0.f ? v : 0.01f * v;
                ssum[h] += __expf(v - m[h]);
            }
        } else {
            float v = s_src[s] + sdv[0];
            v = v > 0.f ? v : 0.01f * v;
            ssum[0] += __expf(v - m[0]);
        }
    }
    #pragma unroll
    for (int h = 0; h < H; ++h) {
        #pragma unroll
        for (int off = 1; off < 64; off <<= 1)
            ssum[h] += __shfl_xor(ssum[h], off, 64);
    }
    float inv[H];
    #pragma unroll
    for (int h = 0; h < H; ++h) inv[h] = 1.0f / fmaxf(ssum[h], 1e-9f);

    // ---- pass 3: chunked alpha + accumulate (bf16 gathers) ----
    const int myh = (H == 4) ? (lane >> 4) : 0;
    float2 acc = make_float2(0.f, 0.f);
    for (int k = 0; k < nch; ++k) {
        const int base = beg + k * 128;
        int cnt = end - base;
        cnt = cnt < 0 ? 0 : (cnt > 128 ? 128 : cnt);
        for (int idx = lane; idx < cnt; idx += 64) {
            const int s = es[base + idx];
            es_sh[wid][idx] = s;
            if (H == 4) {
                const float4 sv = *(const float4*)&s_src[(size_t)s * 4];
                const float svv[4] = {sv.x, sv.y, sv.z, sv.w};
                float a4[4];
                #pragma unroll
                for (int h = 0; h < 4; ++h) {
                    float v = svv[h] + sdv[h];
                    v = v > 0.f ? v : 0.01f * v;
                    a4[h] = __expf(v - m[h]) * inv[h];
                }
                *(float4*)&alpha_sh[wid][idx][0] = make_float4(a4[0], a4[1], a4[2], a4[3]);
            } else {
                float v = s_src[s] + sdv[0];
                v = v > 0.f ? v : 0.01f * v;
                alpha_sh[wid][idx][0] = __expf(v - m[0]) * inv[0];
            }
        }
        __syncthreads();
        int j = 0;
        for (; j + 2 <= cnt; j += 2) {
            const int s0 = es_sh[wid][j],     s1 = es_sh[wid][j + 1];
            const float a0 = alpha_sh[wid][j][myh], a1 = alpha_sh[wid][j + 1][myh];
            const ushort2 u0 = *(const ushort2*)&z16[(size_t)s0 * CH + lane * 2];
            const ushort2 u1 = *(const ushort2*)&z16[(size_t)s1 * CH + lane * 2];
            acc.x = fmaf(a0, bf16_to_f(u0.x), acc.x); acc.y = fmaf(a0, bf16_to_f(u0.y), acc.y);
            acc.x = fmaf(a1, bf16_to_f(u1.x), acc.x); acc.y = fmaf(a1, bf16_to_f(u1.y), acc.y);
        }
        if (j < cnt) {
            const int s0 = es_sh[wid][j];
            const float a0 = alpha_sh[wid][j][myh];
            const ushort2 u0 = *(const ushort2*)&z16[(size_t)s0 * CH + lane * 2];
            acc.x = fmaf(a0, bf16_to_f(u0.x), acc.x); acc.y = fmaf(a0, bf16_to_f(u0.y), acc.y);
        }
        __syncthreads();
    }

    if (ELU) {
        acc.x = acc.x > 0.f ? acc.x : expm1f(acc.x);
        acc.y = acc.y > 0.f ? acc.y : expm1f(acc.y);
    }
    *(float2*)&out[(size_t)n * CH + lane * 2] = acc;
}

// ---------------- host ----------------
extern "C" void kernel_launch(void* const* d_in, const int* in_sizes, int n_in,
                              void* d_out, int out_size, void* d_ws, size_t ws_size,
                              hipStream_t stream)
{
    const float* h   = (const float*)d_in[0];
    const float* W1  = (const float*)d_in[1];
    const float* a1  = (const float*)d_in[2];
    const float* W2  = (const float*)d_in[3];
    const float* a2  = (const float*)d_in[4];
    const int*   src = (const int*)d_in[5];
    const int*   dst = (const int*)d_in[6];
    float* out = (float*)d_out;

    char* ws = (char*)d_ws;
    unsigned short* Bthi1 = (unsigned short*)(ws + 0);          // 192KB
    unsigned short* Btlo1 = (unsigned short*)(ws + 196608);     // 192KB
    unsigned short* Bthi2 = (unsigned short*)(ws + 393216);     // 32KB
    unsigned short* Btlo2 = (unsigned short*)(ws + 425984);     // 32KB
    float* ss      = (float*)(ws + 458752);                     // 800KB
    float* sd      = (float*)(ws + 1258752);                    // 800KB
    int*   counts  = (int*)  (ws + 2058752);                    // 200KB
    int*   exc     = (int*)  (ws + 2258752);                    // 200KB
    int*   bsum    = (int*)  (ws + 2458752);                    // 1KB
    int*   bexc    = (int*)  (ws + 2459776);                    // 1KB
    int*   offsets = (int*)  (ws + 2460800);                    // 200KB+4
    int*   cursor  = (int*)  (ws + 2661056);                    // 200KB
    int*   es      = (int*)  (ws + 2861056);                    // 3.2MB
    unsigned short* z16 = (unsigned short*)(ws + 6061056);      // 12.8MB
    float* h1      = (float*)(ws + 18861056);                   // 25.6MB
    float* P       = (float*)(ws + 45075456);                   // 51.2MB (2 partials)

    const int EB = 256;
    const int egrid = (NE + EB - 1) / EB;
    const int sgrid = NN / 4;

    // --- CSR build (shared by both layers) ---
    zero_cc<<<NBLK, 256, 0, stream>>>(counts, cursor);
    count_k<<<egrid, EB, 0, stream>>>(dst, counts);
    scan1<<<NBLK, 256, 0, stream>>>(counts, exc, bsum);
    scan2<<<1, 256, 0, stream>>>(bsum, bexc);
    scan3<<<NBLK, 256, 0, stream>>>(exc, bexc, offsets);
    scatter_es<<<egrid, EB, 0, stream>>>(src, dst, offsets, cursor, es);

    // --- weight prep (split bf16, tiled+swizzled) ---
    prep_b1<<<(CH * IND + 255) / 256, 256, 0, stream>>>(W1, Bthi1, Btlo1);
    prep_b2<<<(CH * CH + 255) / 256, 256, 0, stream>>>(W2, Bthi2, Btlo2);

    // --- layer 1: split-K x2 GEMM -> reduce(+s) -> aggregate ---
    gemm_ks<<<MBLKS * 2, 256, 0, stream>>>(h, Bthi1, Btlo1, P, IND, 2);
    reduce_s<4, 2><<<sgrid, 256, 0, stream>>>(P, a1, z16, ss, sd);
    fused_agg<4, true><<<sgrid, 256, 0, stream>>>(offsets, es, ss, sd, z16, h1);

    // --- layer 2: KS=1 GEMM -> reduce(+s) -> aggregate ---
    gemm_ks<<<MBLKS, 256, 0, stream>>>(h1, Bthi2, Btlo2, P, CH, 1);
    reduce_s<1, 1><<<sgrid, 256, 0, stream>>>(P, a2, z16, ss, sd);
    fused_agg<1, false><<<sgrid, 256, 0, stream>>>(offsets, es, ss, sd, z16, out);
}

// Round 13
// 269.871 us; speedup vs baseline: 1.1737x; 1.1737x over previous
//
#include <hip/hip_runtime.h>

#define NN 50000
#define NE 800000
#define IND 768
#define CH  128    // output channels per node for both layers
#define NBLK 196   // ceil(NN/256)
#define GBM 64
#define GBK 32
#define MBLKS 782  // ceil(NN/GBM)

typedef __attribute__((ext_vector_type(8))) short bf16x8;
typedef __attribute__((ext_vector_type(4))) float f32x4;

// ---------------- bf16 split helpers ----------------
__device__ __forceinline__ unsigned short bf16_rne(float f) {
    unsigned u = __float_as_uint(f);
    u += 0x7fffu + ((u >> 16) & 1u);
    return (unsigned short)(u >> 16);
}
__device__ __forceinline__ float bf16_to_f(unsigned short b) {
    return __uint_as_float(((unsigned)b) << 16);
}

// ---------------- prep: W -> K-tiled, 8-way-swizzled bf16 hi/lo planes ----------------
__global__ void prep_b1(const float* __restrict__ W1,
                        unsigned short* __restrict__ Bhi, unsigned short* __restrict__ Blo)
{
    int idx = blockIdx.x * blockDim.x + threadIdx.x;   // n*IND + k
    if (idx >= CH * IND) return;
    int n = idx / IND, k = idx % IND;
    float v = W1[(size_t)(n >> 5) * IND * 32 + (size_t)k * 32 + (n & 31)];
    int kt = k >> 5, kk = k & 31, j = kk >> 3, e = kk & 7;
    int g = n * 4 + (j ^ ((n >> 1) & 3));
    int off = kt * 4096 + g * 8 + e;
    unsigned short hi = bf16_rne(v);
    float lo = v - bf16_to_f(hi);
    Bhi[off] = hi;
    Blo[off] = bf16_rne(lo);
}

__global__ void prep_b2(const float* __restrict__ W2,
                        unsigned short* __restrict__ Bhi, unsigned short* __restrict__ Blo)
{
    int idx = blockIdx.x * blockDim.x + threadIdx.x;   // n*CH + k
    if (idx >= CH * CH) return;
    int n = idx / CH, k = idx % CH;
    float v = W2[(size_t)k * CH + n];
    int kt = k >> 5, kk = k & 31, j = kk >> 3, e = kk & 7;
    int g = n * 4 + (j ^ ((n >> 1) & 3));
    int off = kt * 4096 + g * 8 + e;
    unsigned short hi = bf16_rne(v);
    float lo = v - bf16_to_f(hi);
    Bhi[off] = hi;
    Blo[off] = bf16_rne(lo);
}

// ---------------- GEMM with fused epilogue: z16 + s_src/s_dst ----------------
// Round-6/11 schedule (proven best): single-buffer, sync A stage, global_load_lds B.
// Block 256 thr = 4 waves (2x2), wave tile 32x64. Epilogue computes per-head scores.
template<int H>
__global__ __launch_bounds__(256) void gemm_fused(
    const float* __restrict__ A,
    const unsigned short* __restrict__ Bthi, const unsigned short* __restrict__ Btlo,
    const float* __restrict__ av,            // attention vec: [H][2*(128/H)]
    unsigned short* __restrict__ Z16,
    float* __restrict__ ss, float* __restrict__ sd, int K)
{
    __shared__ unsigned short Ahi[2048];
    __shared__ unsigned short Alo[2048];
    __shared__ unsigned short Bs[2][4096];
    __shared__ float sred[2][64][2];         // H==1 cross-wave reduce (src/dst, row, wc)

    const int t = threadIdx.x;
    const int lane = t & 63;
    const int w = t >> 6;
    const int wr = w >> 1, wc = w & 1;
    const int lrow = lane & 15, kg = lane >> 4;
    const int m0 = blockIdx.x * GBM;
    const int nt = K >> 5;

    const int ar = t >> 2, aj = t & 3;
    const bool avalid = (m0 + ar) < NN;
    const float* aptr = A + (size_t)(avalid ? (m0 + ar) : 0) * K + aj * 8;
    const int ag8 = (ar * 4 + (aj ^ ((ar >> 1) & 3))) * 8;

    int aoff[2];
    #pragma unroll
    for (int mi = 0; mi < 2; ++mi) {
        const int r = wr * 32 + mi * 16 + lrow;
        aoff[mi] = (r * 4 + (kg ^ ((r >> 1) & 3))) * 8;
    }
    int boff[4];
    #pragma unroll
    for (int ni = 0; ni < 4; ++ni) {
        const int n = wc * 64 + ni * 16 + lrow;
        boff[ni] = (n * 4 + (kg ^ ((n >> 1) & 3))) * 8;
    }

    f32x4 acc[2][4];
    #pragma unroll
    for (int i = 0; i < 2; ++i)
        #pragma unroll
        for (int j = 0; j < 4; ++j) acc[i][j] = (f32x4)(0.f);

    for (int kt = 0; kt < nt; ++kt) {
        float4 v0 = make_float4(0.f, 0.f, 0.f, 0.f);
        float4 v1 = make_float4(0.f, 0.f, 0.f, 0.f);
        if (avalid) {
            const float* p = aptr + kt * GBK;
            v0 = *(const float4*)p;
            v1 = *(const float4*)(p + 4);
        }
        float f[8] = {v0.x, v0.y, v0.z, v0.w, v1.x, v1.y, v1.z, v1.w};
        unsigned short hi[8], lo[8];
        #pragma unroll
        for (int q = 0; q < 8; ++q) {
            hi[q] = bf16_rne(f[q]);
            lo[q] = bf16_rne(f[q] - bf16_to_f(hi[q]));
        }
        __syncthreads();
        *(uint4*)&Ahi[ag8] = *(uint4*)hi;
        *(uint4*)&Alo[ag8] = *(uint4*)lo;
        #pragma unroll
        for (int i = 0; i < 4; ++i) {
            const int c = w * 4 + i;
            const int plane = c >> 3;
            const int co = (c & 7) * 512;
            const unsigned short* gs =
                (plane ? Btlo : Bthi) + (size_t)kt * 4096 + co + lane * 8;
            __builtin_amdgcn_global_load_lds(
                (const __attribute__((address_space(1))) unsigned int*)gs,
                (__attribute__((address_space(3))) unsigned int*)&Bs[plane][co],
                16, 0, 0);
        }
        __syncthreads();

        bf16x8 ahi[2], alo[2];
        #pragma unroll
        for (int mi = 0; mi < 2; ++mi) {
            ahi[mi] = *(const bf16x8*)&Ahi[aoff[mi]];
            alo[mi] = *(const bf16x8*)&Alo[aoff[mi]];
        }
        #pragma unroll
        for (int ni = 0; ni < 4; ++ni) {
            const bf16x8 bhi = *(const bf16x8*)&Bs[0][boff[ni]];
            const bf16x8 blo = *(const bf16x8*)&Bs[1][boff[ni]];
            #pragma unroll
            for (int mi = 0; mi < 2; ++mi) {
                acc[mi][ni] = __builtin_amdgcn_mfma_f32_16x16x32_bf16(ahi[mi], bhi, acc[mi][ni], 0, 0, 0);
                acc[mi][ni] = __builtin_amdgcn_mfma_f32_16x16x32_bf16(ahi[mi], blo, acc[mi][ni], 0, 0, 0);
                acc[mi][ni] = __builtin_amdgcn_mfma_f32_16x16x32_bf16(alo[mi], bhi, acc[mi][ni], 0, 0, 0);
            }
        }
    }

    // ---- epilogue: z16 store + per-head score dots ----
    // lane's element (mi,ni,j): row = m0+wr*32+mi*16+kg*4+j, col = wc*64+ni*16+lrow
    const int NH = (H == 4) ? 2 : 1;         // local heads per wc-half
    float asc[4], adc[4];
    #pragma unroll
    for (int ni = 0; ni < 4; ++ni) {
        const int col = wc * 64 + ni * 16 + lrow;
        if (H == 4) {
            const int hh = col >> 5, d = col & 31;
            asc[ni] = av[hh * 64 + d];
            adc[ni] = av[hh * 64 + 32 + d];
        } else {
            asc[ni] = av[col];
            adc[ni] = av[128 + col];
        }
    }
    float es[2][4][2], ed[2][4][2];
    #pragma unroll
    for (int mi = 0; mi < 2; ++mi)
        #pragma unroll
        for (int j = 0; j < 4; ++j)
            #pragma unroll
            for (int q = 0; q < 2; ++q) { es[mi][j][q] = 0.f; ed[mi][j][q] = 0.f; }

    #pragma unroll
    for (int mi = 0; mi < 2; ++mi) {
        #pragma unroll
        for (int ni = 0; ni < 4; ++ni) {
            const int hh = (H == 4) ? (ni >> 1) : 0;
            const f32x4 a = acc[mi][ni];
            #pragma unroll
            for (int j = 0; j < 4; ++j) {
                es[mi][j][hh] = fmaf(a[j], asc[ni], es[mi][j][hh]);
                ed[mi][j][hh] = fmaf(a[j], adc[ni], ed[mi][j][hh]);
            }
        }
    }
    // z16 store
    #pragma unroll
    for (int mi = 0; mi < 2; ++mi) {
        const int rbase = m0 + wr * 32 + mi * 16 + kg * 4;
        #pragma unroll
        for (int ni = 0; ni < 4; ++ni) {
            const int col = wc * 64 + ni * 16 + lrow;
            const f32x4 a = acc[mi][ni];
            #pragma unroll
            for (int j = 0; j < 4; ++j) {
                const int r = rbase + j;
                if (r < NN) Z16[(size_t)r * CH + col] = bf16_rne(a[j]);
            }
        }
    }
    // reduce score partials across the 16 lrow lanes
    #pragma unroll
    for (int off = 1; off < 16; off <<= 1) {
        #pragma unroll
        for (int mi = 0; mi < 2; ++mi)
            #pragma unroll
            for (int j = 0; j < 4; ++j)
                #pragma unroll
                for (int q = 0; q < NH; ++q) {
                    es[mi][j][q] += __shfl_xor(es[mi][j][q], off, 64);
                    ed[mi][j][q] += __shfl_xor(ed[mi][j][q], off, 64);
                }
    }
    if (H == 4) {
        // head h = wc*2+hh lives entirely in this wc-half: direct store
        if (lrow == 0) {
            #pragma unroll
            for (int mi = 0; mi < 2; ++mi)
                #pragma unroll
                for (int j = 0; j < 4; ++j) {
                    const int r = m0 + wr * 32 + mi * 16 + kg * 4 + j;
                    if (r < NN) {
                        #pragma unroll
                        for (int q = 0; q < 2; ++q) {
                            ss[r * 4 + wc * 2 + q] = es[mi][j][q];
                            sd[r * 4 + wc * 2 + q] = ed[mi][j][q];
                        }
                    }
                }
        }
    } else {
        // single head spans both wc halves: LDS reduce
        if (lrow == 0) {
            #pragma unroll
            for (int mi = 0; mi < 2; ++mi)
                #pragma unroll
                for (int j = 0; j < 4; ++j) {
                    const int rl = wr * 32 + mi * 16 + kg * 4 + j;
                    sred[0][rl][wc] = es[mi][j][0];
                    sred[1][rl][wc] = ed[mi][j][0];
                }
        }
        __syncthreads();
        if (t < 64) {
            const int r = m0 + t;
            if (r < NN) {
                ss[r] = sred[0][t][0] + sred[0][t][1];
                sd[r] = sred[1][t][0] + sred[1][t][1];
            }
        }
    }
}

// ---------------- CSR build ----------------
__global__ __launch_bounds__(256) void zero_cc(int* __restrict__ counts, int* __restrict__ cursor)
{
    int i = blockIdx.x * 256 + threadIdx.x;
    if (i < NN) { counts[i] = 0; cursor[i] = 0; }
}

__global__ void count_k(const int* __restrict__ dst, int* __restrict__ counts)
{
    int e = blockIdx.x * blockDim.x + threadIdx.x;
    if (e < NE) atomicAdd(&counts[dst[e]], 1);
}

__global__ __launch_bounds__(256) void scan1(const int* __restrict__ counts,
                                             int* __restrict__ exc, int* __restrict__ bsum)
{
    __shared__ int s[256];
    const int t = threadIdx.x;
    const int i = blockIdx.x * 256 + t;
    const int val = (i < NN) ? counts[i] : 0;
    s[t] = val;
    __syncthreads();
    #pragma unroll
    for (int off = 1; off < 256; off <<= 1) {
        int v = (t >= off) ? s[t - off] : 0;
        __syncthreads();
        s[t] += v;
        __syncthreads();
    }
    if (i < NN) exc[i] = s[t] - val;
    if (t == 255) bsum[blockIdx.x] = s[255];
}

__global__ __launch_bounds__(256) void scan2(const int* __restrict__ bsum,
                                             int* __restrict__ bexc)
{
    __shared__ int s[256];
    const int t = threadIdx.x;
    const int val = (t < NBLK) ? bsum[t] : 0;
    s[t] = val;
    __syncthreads();
    #pragma unroll
    for (int off = 1; off < 256; off <<= 1) {
        int v = (t >= off) ? s[t - off] : 0;
        __syncthreads();
        s[t] += v;
        __syncthreads();
    }
    bexc[t] = s[t] - val;
}

__global__ __launch_bounds__(256) void scan3(const int* __restrict__ exc,
                                             const int* __restrict__ bexc,
                                             int* __restrict__ offsets)
{
    const int i = blockIdx.x * 256 + threadIdx.x;
    if (i < NN) offsets[i] = exc[i] + bexc[i >> 8];
    if (i == 0) offsets[NN] = NE;
}

__global__ void scatter_es(const int* __restrict__ src, const int* __restrict__ dst,
                           const int* __restrict__ offsets, int* __restrict__ cursor,
                           int* __restrict__ es)
{
    int e = blockIdx.x * blockDim.x + threadIdx.x;
    if (e >= NE) return;
    int d = dst[e];
    int p = offsets[d] + atomicAdd(&cursor[d], 1);
    es[p] = src[e];
}

// ---------------- fused softmax + aggregation: one WAVE per dst node ----------------
// Online-softmax first pass (single gather round), then chunked alpha+accumulate.
template<int H, bool ELU>
__global__ __launch_bounds__(256) void fused_agg(
    const int* __restrict__ offsets, const int* __restrict__ es,
    const float* __restrict__ s_src, const float* __restrict__ s_dst,
    const unsigned short* __restrict__ z16, float* __restrict__ out)
{
    const int wid = threadIdx.x >> 6;
    const int lane = threadIdx.x & 63;
    const int n = blockIdx.x * 4 + wid;     // NN % 4 == 0
    const int beg = offsets[n], end = offsets[n + 1];
    const int deg = end - beg;

    __shared__ float alpha_sh[4][128][H];
    __shared__ int   es_sh[4][128];
    __shared__ int   maxdeg;
    if (threadIdx.x == 0) maxdeg = 0;
    __syncthreads();
    if (lane == 0) atomicMax(&maxdeg, deg);
    __syncthreads();
    const int nch = (maxdeg + 127) >> 7;    // uniform across block

    float sdv[H];
    #pragma unroll
    for (int h = 0; h < H; ++h) sdv[h] = s_dst[(size_t)n * H + h];

    // ---- pass 1 (online): per-lane running max + sum ----
    float m[H], ssum[H];
    #pragma unroll
    for (int h = 0; h < H; ++h) { m[h] = -INFINITY; ssum[h] = 0.f; }
    for (int i = beg + lane; i < end; i += 64) {
        const int s = es[i];
        if (H == 4) {
            const float4 sv = *(const float4*)&s_src[(size_t)s * 4];
            const float svv[4] = {sv.x, sv.y, sv.z, sv.w};
            #pragma unroll
            for (int h = 0; h < 4; ++h) {
                float v = svv[h] + sdv[h];
                v = v > 0.f ? v : 0.01f * v;
                const float mn = fmaxf(m[h], v);
                ssum[h] = ssum[h] * __expf(m[h] - mn) + __expf(v - mn);
                m[h] = mn;
            }
        } else {
            float v = s_src[s] + sdv[0];
            v = v > 0.f ? v : 0.01f * v;
            const float mn = fmaxf(m[0], v);
            ssum[0] = ssum[0] * __expf(m[0] - mn) + __expf(v - mn);
            m[0] = mn;
        }
    }
    // cross-lane: global max, then scaled sum
    float inv[H];
    #pragma unroll
    for (int h = 0; h < H; ++h) {
        float mg = m[h];
        #pragma unroll
        for (int off = 1; off < 64; off <<= 1)
            mg = fmaxf(mg, __shfl_xor(mg, off, 64));
        float sg = ssum[h] * __expf(m[h] - mg);   // lanes with no edges: 0*exp(-inf)=0
        #pragma unroll
        for (int off = 1; off < 64; off <<= 1)
            sg += __shfl_xor(sg, off, 64);
        m[h] = mg;
        inv[h] = 1.0f / fmaxf(sg, 1e-9f);
    }

    // ---- pass 2: chunked alpha + accumulate (bf16 gathers) ----
    const int myh = (H == 4) ? (lane >> 4) : 0;
    float2 acc = make_float2(0.f, 0.f);
    for (int k = 0; k < nch; ++k) {
        const int base = beg + k * 128;
        int cnt = end - base;
        cnt = cnt < 0 ? 0 : (cnt > 128 ? 128 : cnt);
        for (int idx = lane; idx < cnt; idx += 64) {
            const int s = es[base + idx];
            es_sh[wid][idx] = s;
            if (H == 4) {
                const float4 sv = *(const float4*)&s_src[(size_t)s * 4];
                const float svv[4] = {sv.x, sv.y, sv.z, sv.w};
                float a4[4];
                #pragma unroll
                for (int h = 0; h < 4; ++h) {
                    float v = svv[h] + sdv[h];
                    v = v > 0.f ? v : 0.01f * v;
                    a4[h] = __expf(v - m[h]) * inv[h];
                }
                *(float4*)&alpha_sh[wid][idx][0] = make_float4(a4[0], a4[1], a4[2], a4[3]);
            } else {
                float v = s_src[s] + sdv[0];
                v = v > 0.f ? v : 0.01f * v;
                alpha_sh[wid][idx][0] = __expf(v - m[0]) * inv[0];
            }
        }
        __syncthreads();
        int j = 0;
        for (; j + 2 <= cnt; j += 2) {
            const int s0 = es_sh[wid][j],     s1 = es_sh[wid][j + 1];
            const float a0 = alpha_sh[wid][j][myh], a1 = alpha_sh[wid][j + 1][myh];
            const ushort2 u0 = *(const ushort2*)&z16[(size_t)s0 * CH + lane * 2];
            const ushort2 u1 = *(const ushort2*)&z16[(size_t)s1 * CH + lane * 2];
            acc.x = fmaf(a0, bf16_to_f(u0.x), acc.x); acc.y = fmaf(a0, bf16_to_f(u0.y), acc.y);
            acc.x = fmaf(a1, bf16_to_f(u1.x), acc.x); acc.y = fmaf(a1, bf16_to_f(u1.y), acc.y);
        }
        if (j < cnt) {
            const int s0 = es_sh[wid][j];
            const float a0 = alpha_sh[wid][j][myh];
            const ushort2 u0 = *(const ushort2*)&z16[(size_t)s0 * CH + lane * 2];
            acc.x = fmaf(a0, bf16_to_f(u0.x), acc.x); acc.y = fmaf(a0, bf16_to_f(u0.y), acc.y);
        }
        __syncthreads();
    }

    if (ELU) {
        acc.x = acc.x > 0.f ? acc.x : expm1f(acc.x);
        acc.y = acc.y > 0.f ? acc.y : expm1f(acc.y);
    }
    *(float2*)&out[(size_t)n * CH + lane * 2] = acc;
}

// ---------------- host ----------------
extern "C" void kernel_launch(void* const* d_in, const int* in_sizes, int n_in,
                              void* d_out, int out_size, void* d_ws, size_t ws_size,
                              hipStream_t stream)
{
    const float* h   = (const float*)d_in[0];
    const float* W1  = (const float*)d_in[1];
    const float* a1  = (const float*)d_in[2];
    const float* W2  = (const float*)d_in[3];
    const float* a2  = (const float*)d_in[4];
    const int*   src = (const int*)d_in[5];
    const int*   dst = (const int*)d_in[6];
    float* out = (float*)d_out;

    char* ws = (char*)d_ws;
    unsigned short* Bthi1 = (unsigned short*)(ws + 0);          // 192KB
    unsigned short* Btlo1 = (unsigned short*)(ws + 196608);     // 192KB
    unsigned short* Bthi2 = (unsigned short*)(ws + 393216);     // 32KB
    unsigned short* Btlo2 = (unsigned short*)(ws + 425984);     // 32KB
    float* ss      = (float*)(ws + 458752);                     // 800KB
    float* sd      = (float*)(ws + 1258752);                    // 800KB
    int*   counts  = (int*)  (ws + 2058752);                    // 200KB
    int*   exc     = (int*)  (ws + 2258752);                    // 200KB
    int*   bsum    = (int*)  (ws + 2458752);                    // 1KB
    int*   bexc    = (int*)  (ws + 2459776);                    // 1KB
    int*   offsets = (int*)  (ws + 2460800);                    // 200KB+4
    int*   cursor  = (int*)  (ws + 2661056);                    // 200KB
    int*   es      = (int*)  (ws + 2861056);                    // 3.2MB
    unsigned short* z16 = (unsigned short*)(ws + 6061056);      // 12.8MB
    float* h1      = (float*)(ws + 18861056);                   // 25.6MB

    const int EB = 256;
    const int egrid = (NE + EB - 1) / EB;
    const int sgrid = NN / 4;

    // --- CSR build (shared by both layers) ---
    zero_cc<<<NBLK, 256, 0, stream>>>(counts, cursor);
    count_k<<<egrid, EB, 0, stream>>>(dst, counts);
    scan1<<<NBLK, 256, 0, stream>>>(counts, exc, bsum);
    scan2<<<1, 256, 0, stream>>>(bsum, bexc);
    scan3<<<NBLK, 256, 0, stream>>>(exc, bexc, offsets);
    scatter_es<<<egrid, EB, 0, stream>>>(src, dst, offsets, cursor, es);

    // --- weight prep (split bf16, tiled+swizzled) ---
    prep_b1<<<(CH * IND + 255) / 256, 256, 0, stream>>>(W1, Bthi1, Btlo1);
    prep_b2<<<(CH * CH + 255) / 256, 256, 0, stream>>>(W2, Bthi2, Btlo2);

    // --- layer 1: GEMM (fused z16 + scores) -> aggregate ---
    gemm_fused<4><<<MBLKS, 256, 0, stream>>>(h, Bthi1, Btlo1, a1, z16, ss, sd, IND);
    fused_agg<4, true><<<sgrid, 256, 0, stream>>>(offsets, es, ss, sd, z16, h1);

    // --- layer 2: GEMM (fused z16 + scores) -> aggregate ---
    gemm_fused<1><<<MBLKS, 256, 0, stream>>>(h1, Bthi2, Btlo2, a2, z16, ss, sd, CH);
    fused_agg<1, false><<<sgrid, 256, 0, stream>>>(offsets, es, ss, sd, z16, out);
}

// Round 14
// 245.314 us; speedup vs baseline: 1.2912x; 1.1001x over previous
//
#include <hip/hip_runtime.h>

#define NN 50000
#define NE 800000
#define IND 768
#define CH  128    // output channels per node for both layers
#define NBLK 196   // ceil(NN/256)
#define GBM 64
#define GBK 32
#define MBLKS 782  // ceil(NN/GBM)

typedef __attribute__((ext_vector_type(8))) short bf16x8;
typedef __attribute__((ext_vector_type(4))) float f32x4;

// ---------------- bf16 split helpers ----------------
__device__ __forceinline__ unsigned short bf16_rne(float f) {
    unsigned u = __float_as_uint(f);
    u += 0x7fffu + ((u >> 16) & 1u);
    return (unsigned short)(u >> 16);
}
__device__ __forceinline__ float bf16_to_f(unsigned short b) {
    return __uint_as_float(((unsigned)b) << 16);
}

// fast split via packed cvt: hi = cvt_pk(v), lo = cvt_pk(v - hi)
__device__ __forceinline__ void cvt_split_pk(const float4& u0, const float4& u1,
                                             uint4& hi, uint4& lo)
{
    unsigned h0, h1, h2, h3;
    asm("v_cvt_pk_bf16_f32 %0, %1, %2" : "=v"(h0) : "v"(u0.x), "v"(u0.y));
    asm("v_cvt_pk_bf16_f32 %0, %1, %2" : "=v"(h1) : "v"(u0.z), "v"(u0.w));
    asm("v_cvt_pk_bf16_f32 %0, %1, %2" : "=v"(h2) : "v"(u1.x), "v"(u1.y));
    asm("v_cvt_pk_bf16_f32 %0, %1, %2" : "=v"(h3) : "v"(u1.z), "v"(u1.w));
    const float l0 = u0.x - __uint_as_float(h0 << 16);
    const float l1 = u0.y - __uint_as_float(h0 & 0xffff0000u);
    const float l2 = u0.z - __uint_as_float(h1 << 16);
    const float l3 = u0.w - __uint_as_float(h1 & 0xffff0000u);
    const float l4 = u1.x - __uint_as_float(h2 << 16);
    const float l5 = u1.y - __uint_as_float(h2 & 0xffff0000u);
    const float l6 = u1.z - __uint_as_float(h3 << 16);
    const float l7 = u1.w - __uint_as_float(h3 & 0xffff0000u);
    unsigned g0, g1, g2, g3;
    asm("v_cvt_pk_bf16_f32 %0, %1, %2" : "=v"(g0) : "v"(l0), "v"(l1));
    asm("v_cvt_pk_bf16_f32 %0, %1, %2" : "=v"(g1) : "v"(l2), "v"(l3));
    asm("v_cvt_pk_bf16_f32 %0, %1, %2" : "=v"(g2) : "v"(l4), "v"(l5));
    asm("v_cvt_pk_bf16_f32 %0, %1, %2" : "=v"(g3) : "v"(l6), "v"(l7));
    hi = make_uint4(h0, h1, h2, h3);
    lo = make_uint4(g0, g1, g2, g3);
}

// ---------------- prep: W -> K-tiled, 8-way-swizzled bf16 hi/lo planes ----------------
__global__ void prep_b1(const float* __restrict__ W1,
                        unsigned short* __restrict__ Bhi, unsigned short* __restrict__ Blo)
{
    int idx = blockIdx.x * blockDim.x + threadIdx.x;   // n*IND + k
    if (idx >= CH * IND) return;
    int n = idx / IND, k = idx % IND;
    float v = W1[(size_t)(n >> 5) * IND * 32 + (size_t)k * 32 + (n & 31)];
    int kt = k >> 5, kk = k & 31, j = kk >> 3, e = kk & 7;
    int g = n * 4 + (j ^ ((n >> 1) & 3));
    int off = kt * 4096 + g * 8 + e;
    unsigned short hi = bf16_rne(v);
    float lo = v - bf16_to_f(hi);
    Bhi[off] = hi;
    Blo[off] = bf16_rne(lo);
}

__global__ void prep_b2(const float* __restrict__ W2,
                        unsigned short* __restrict__ Bhi, unsigned short* __restrict__ Blo)
{
    int idx = blockIdx.x * blockDim.x + threadIdx.x;   // n*CH + k
    if (idx >= CH * CH) return;
    int n = idx / CH, k = idx % CH;
    float v = W2[(size_t)k * CH + n];
    int kt = k >> 5, kk = k & 31, j = kk >> 3, e = kk & 7;
    int g = n * 4 + (j ^ ((n >> 1) & 3));
    int off = kt * 4096 + g * 8 + e;
    unsigned short hi = bf16_rne(v);
    float lo = v - bf16_to_f(hi);
    Bhi[off] = hi;
    Blo[off] = bf16_rne(lo);
}

// ---------------- GEMM with fused epilogue: z16 + s_src/s_dst ----------------
template<int H>
__global__ __launch_bounds__(256) void gemm_fused(
    const float* __restrict__ A,
    const unsigned short* __restrict__ Bthi, const unsigned short* __restrict__ Btlo,
    const float* __restrict__ av,            // attention vec: [H][2*(128/H)]
    unsigned short* __restrict__ Z16,
    float* __restrict__ ss, float* __restrict__ sd, int K)
{
    __shared__ unsigned short Ahi[2048];
    __shared__ unsigned short Alo[2048];
    __shared__ unsigned short Bs[2][4096];
    __shared__ float sred[2][64][2];         // H==1 cross-wave reduce

    const int t = threadIdx.x;
    const int lane = t & 63;
    const int w = t >> 6;
    const int wr = w >> 1, wc = w & 1;
    const int lrow = lane & 15, kg = lane >> 4;
    const int m0 = blockIdx.x * GBM;
    const int nt = K >> 5;

    const int ar = t >> 2, aj = t & 3;
    const bool avalid = (m0 + ar) < NN;
    const float* aptr = A + (size_t)(avalid ? (m0 + ar) : 0) * K + aj * 8;
    const int ag8 = (ar * 4 + (aj ^ ((ar >> 1) & 3))) * 8;

    int aoff[2];
    #pragma unroll
    for (int mi = 0; mi < 2; ++mi) {
        const int r = wr * 32 + mi * 16 + lrow;
        aoff[mi] = (r * 4 + (kg ^ ((r >> 1) & 3))) * 8;
    }
    int boff[4];
    #pragma unroll
    for (int ni = 0; ni < 4; ++ni) {
        const int n = wc * 64 + ni * 16 + lrow;
        boff[ni] = (n * 4 + (kg ^ ((n >> 1) & 3))) * 8;
    }

    f32x4 acc[2][4];
    #pragma unroll
    for (int i = 0; i < 2; ++i)
        #pragma unroll
        for (int j = 0; j < 4; ++j) acc[i][j] = (f32x4)(0.f);

    for (int kt = 0; kt < nt; ++kt) {
        float4 v0 = make_float4(0.f, 0.f, 0.f, 0.f);
        float4 v1 = make_float4(0.f, 0.f, 0.f, 0.f);
        if (avalid) {
            const float* p = aptr + kt * GBK;
            v0 = *(const float4*)p;
            v1 = *(const float4*)(p + 4);
        }
        uint4 hi, lo;
        cvt_split_pk(v0, v1, hi, lo);
        __syncthreads();
        *(uint4*)&Ahi[ag8] = hi;
        *(uint4*)&Alo[ag8] = lo;
        #pragma unroll
        for (int i = 0; i < 4; ++i) {
            const int c = w * 4 + i;
            const int plane = c >> 3;
            const int co = (c & 7) * 512;
            const unsigned short* gs =
                (plane ? Btlo : Bthi) + (size_t)kt * 4096 + co + lane * 8;
            __builtin_amdgcn_global_load_lds(
                (const __attribute__((address_space(1))) unsigned int*)gs,
                (__attribute__((address_space(3))) unsigned int*)&Bs[plane][co],
                16, 0, 0);
        }
        __syncthreads();

        bf16x8 ahi[2], alo[2];
        #pragma unroll
        for (int mi = 0; mi < 2; ++mi) {
            ahi[mi] = *(const bf16x8*)&Ahi[aoff[mi]];
            alo[mi] = *(const bf16x8*)&Alo[aoff[mi]];
        }
        #pragma unroll
        for (int ni = 0; ni < 4; ++ni) {
            const bf16x8 bhi = *(const bf16x8*)&Bs[0][boff[ni]];
            const bf16x8 blo = *(const bf16x8*)&Bs[1][boff[ni]];
            #pragma unroll
            for (int mi = 0; mi < 2; ++mi) {
                acc[mi][ni] = __builtin_amdgcn_mfma_f32_16x16x32_bf16(ahi[mi], bhi, acc[mi][ni], 0, 0, 0);
                acc[mi][ni] = __builtin_amdgcn_mfma_f32_16x16x32_bf16(ahi[mi], blo, acc[mi][ni], 0, 0, 0);
                acc[mi][ni] = __builtin_amdgcn_mfma_f32_16x16x32_bf16(alo[mi], bhi, acc[mi][ni], 0, 0, 0);
            }
        }
    }

    // ---- epilogue: z16 store + per-head score dots ----
    const int NH = (H == 4) ? 2 : 1;
    float asc[4], adc[4];
    #pragma unroll
    for (int ni = 0; ni < 4; ++ni) {
        const int col = wc * 64 + ni * 16 + lrow;
        if (H == 4) {
            const int hh = col >> 5, d = col & 31;
            asc[ni] = av[hh * 64 + d];
            adc[ni] = av[hh * 64 + 32 + d];
        } else {
            asc[ni] = av[col];
            adc[ni] = av[128 + col];
        }
    }
    float es[2][4][2], ed[2][4][2];
    #pragma unroll
    for (int mi = 0; mi < 2; ++mi)
        #pragma unroll
        for (int j = 0; j < 4; ++j)
            #pragma unroll
            for (int q = 0; q < 2; ++q) { es[mi][j][q] = 0.f; ed[mi][j][q] = 0.f; }

    #pragma unroll
    for (int mi = 0; mi < 2; ++mi) {
        #pragma unroll
        for (int ni = 0; ni < 4; ++ni) {
            const int hh = (H == 4) ? (ni >> 1) : 0;
            const f32x4 a = acc[mi][ni];
            #pragma unroll
            for (int j = 0; j < 4; ++j) {
                es[mi][j][hh] = fmaf(a[j], asc[ni], es[mi][j][hh]);
                ed[mi][j][hh] = fmaf(a[j], adc[ni], ed[mi][j][hh]);
            }
        }
    }
    #pragma unroll
    for (int mi = 0; mi < 2; ++mi) {
        const int rbase = m0 + wr * 32 + mi * 16 + kg * 4;
        #pragma unroll
        for (int ni = 0; ni < 4; ++ni) {
            const int col = wc * 64 + ni * 16 + lrow;
            const f32x4 a = acc[mi][ni];
            #pragma unroll
            for (int j = 0; j < 4; ++j) {
                const int r = rbase + j;
                if (r < NN) Z16[(size_t)r * CH + col] = bf16_rne(a[j]);
            }
        }
    }
    #pragma unroll
    for (int off = 1; off < 16; off <<= 1) {
        #pragma unroll
        for (int mi = 0; mi < 2; ++mi)
            #pragma unroll
            for (int j = 0; j < 4; ++j)
                #pragma unroll
                for (int q = 0; q < NH; ++q) {
                    es[mi][j][q] += __shfl_xor(es[mi][j][q], off, 64);
                    ed[mi][j][q] += __shfl_xor(ed[mi][j][q], off, 64);
                }
    }
    if (H == 4) {
        if (lrow == 0) {
            #pragma unroll
            for (int mi = 0; mi < 2; ++mi)
                #pragma unroll
                for (int j = 0; j < 4; ++j) {
                    const int r = m0 + wr * 32 + mi * 16 + kg * 4 + j;
                    if (r < NN) {
                        #pragma unroll
                        for (int q = 0; q < 2; ++q) {
                            ss[r * 4 + wc * 2 + q] = es[mi][j][q];
                            sd[r * 4 + wc * 2 + q] = ed[mi][j][q];
                        }
                    }
                }
        }
    } else {
        if (lrow == 0) {
            #pragma unroll
            for (int mi = 0; mi < 2; ++mi)
                #pragma unroll
                for (int j = 0; j < 4; ++j) {
                    const int rl = wr * 32 + mi * 16 + kg * 4 + j;
                    sred[0][rl][wc] = es[mi][j][0];
                    sred[1][rl][wc] = ed[mi][j][0];
                }
        }
        __syncthreads();
        if (t < 64) {
            const int r = m0 + t;
            if (r < NN) {
                ss[r] = sred[0][t][0] + sred[0][t][1];
                sd[r] = sred[1][t][0] + sred[1][t][1];
            }
        }
    }
}

// ---------------- CSR build ----------------
__global__ __launch_bounds__(256) void zero_cc(int* __restrict__ counts, int* __restrict__ cursor)
{
    int i = blockIdx.x * 256 + threadIdx.x;
    if (i < NN) { counts[i] = 0; cursor[i] = 0; }
}

__global__ void count_k(const int* __restrict__ dst, int* __restrict__ counts)
{
    int e = blockIdx.x * blockDim.x + threadIdx.x;
    if (e < NE) atomicAdd(&counts[dst[e]], 1);
}

__global__ __launch_bounds__(256) void scan1(const int* __restrict__ counts,
                                             int* __restrict__ exc, int* __restrict__ bsum)
{
    __shared__ int s[256];
    const int t = threadIdx.x;
    const int i = blockIdx.x * 256 + t;
    const int val = (i < NN) ? counts[i] : 0;
    s[t] = val;
    __syncthreads();
    #pragma unroll
    for (int off = 1; off < 256; off <<= 1) {
        int v = (t >= off) ? s[t - off] : 0;
        __syncthreads();
        s[t] += v;
        __syncthreads();
    }
    if (i < NN) exc[i] = s[t] - val;
    if (t == 255) bsum[blockIdx.x] = s[255];
}

__global__ __launch_bounds__(256) void scan2(const int* __restrict__ bsum,
                                             int* __restrict__ bexc)
{
    __shared__ int s[256];
    const int t = threadIdx.x;
    const int val = (t < NBLK) ? bsum[t] : 0;
    s[t] = val;
    __syncthreads();
    #pragma unroll
    for (int off = 1; off < 256; off <<= 1) {
        int v = (t >= off) ? s[t - off] : 0;
        __syncthreads();
        s[t] += v;
        __syncthreads();
    }
    bexc[t] = s[t] - val;
}

__global__ __launch_bounds__(256) void scan3(const int* __restrict__ exc,
                                             const int* __restrict__ bexc,
                                             int* __restrict__ offsets)
{
    const int i = blockIdx.x * 256 + threadIdx.x;
    if (i < NN) offsets[i] = exc[i] + bexc[i >> 8];
    if (i == 0) offsets[NN] = NE;
}

__global__ void scatter_es(const int* __restrict__ src, const int* __restrict__ dst,
                           const int* __restrict__ offsets, int* __restrict__ cursor,
                           int* __restrict__ es)
{
    int e = blockIdx.x * blockDim.x + threadIdx.x;
    if (e >= NE) return;
    int d = dst[e];
    int p = offsets[d] + atomicAdd(&cursor[d], 1);
    es[p] = src[e];
}

// ---------------- fused softmax + aggregation: one WAVE per dst node ----------------
// Fast path (maxdeg<=128, block-uniform): v cached in wave-private LDS, zero barriers,
// 4-unrolled z16 gathers. Fallback: chunked path with barriers (rare).
template<int H, bool ELU>
__global__ __launch_bounds__(256) void fused_agg(
    const int* __restrict__ offsets, const int* __restrict__ es,
    const float* __restrict__ s_src, const float* __restrict__ s_dst,
    const unsigned short* __restrict__ z16, float* __restrict__ out)
{
    const int wid = threadIdx.x >> 6;
    const int lane = threadIdx.x & 63;
    const int n = blockIdx.x * 4 + wid;     // NN % 4 == 0
    const int beg = offsets[n], end = offsets[n + 1];
    const int deg = end - beg;

    __shared__ float alpha_sh[4][128][H];
    __shared__ int   es_sh[4][128];
    __shared__ int   maxdeg;
    if (threadIdx.x == 0) maxdeg = 0;
    __syncthreads();
    if (lane == 0) atomicMax(&maxdeg, deg);
    __syncthreads();

    float sdv[H];
    #pragma unroll
    for (int h = 0; h < H; ++h) sdv[h] = s_dst[(size_t)n * H + h];

    const int myh = (H == 4) ? (lane >> 4) : 0;
    float m[H], ssum[H], inv[H];
    #pragma unroll
    for (int h = 0; h < H; ++h) { m[h] = -INFINITY; ssum[h] = 0.f; }
    float2 acc = make_float2(0.f, 0.f);

    if (maxdeg <= 128) {
        // ---- pass 1: gather scores once, cache v in wave-private LDS ----
        for (int idx = lane; idx < deg; idx += 64) {
            const int s = es[beg + idx];
            es_sh[wid][idx] = s;
            if (H == 4) {
                const float4 sv = *(const float4*)&s_src[(size_t)s * 4];
                const float svv[4] = {sv.x, sv.y, sv.z, sv.w};
                float v4[4];
                #pragma unroll
                for (int h = 0; h < 4; ++h) {
                    float v = svv[h] + sdv[h];
                    v = v > 0.f ? v : 0.01f * v;
                    v4[h] = v;
                    const float mn = fmaxf(m[h], v);
                    ssum[h] = ssum[h] * __expf(m[h] - mn) + __expf(v - mn);
                    m[h] = mn;
                }
                *(float4*)&alpha_sh[wid][idx][0] = make_float4(v4[0], v4[1], v4[2], v4[3]);
            } else {
                float v = s_src[s] + sdv[0];
                v = v > 0.f ? v : 0.01f * v;
                alpha_sh[wid][idx][0] = v;
                const float mn = fmaxf(m[0], v);
                ssum[0] = ssum[0] * __expf(m[0] - mn) + __expf(v - mn);
                m[0] = mn;
            }
        }
        // ---- wave reduce: global max, scaled sum ----
        #pragma unroll
        for (int h = 0; h < H; ++h) {
            float mg = m[h];
            #pragma unroll
            for (int off = 1; off < 64; off <<= 1)
                mg = fmaxf(mg, __shfl_xor(mg, off, 64));
            float sg = ssum[h] * __expf(m[h] - mg);
            #pragma unroll
            for (int off = 1; off < 64; off <<= 1)
                sg += __shfl_xor(sg, off, 64);
            m[h] = mg;
            inv[h] = 1.0f / fmaxf(sg, 1e-9f);
        }
        // ---- convert cached v -> alpha in place (same lanes that wrote) ----
        for (int idx = lane; idx < deg; idx += 64) {
            #pragma unroll
            for (int h = 0; h < H; ++h)
                alpha_sh[wid][idx][h] = __expf(alpha_sh[wid][idx][h] - m[h]) * inv[h];
        }
        // ---- PV gather, 4-unrolled ----
        int j = 0;
        for (; j + 4 <= deg; j += 4) {
            const int s0 = es_sh[wid][j],     s1 = es_sh[wid][j + 1];
            const int s2 = es_sh[wid][j + 2], s3 = es_sh[wid][j + 3];
            const float a0 = alpha_sh[wid][j][myh],     a1 = alpha_sh[wid][j + 1][myh];
            const float a2 = alpha_sh[wid][j + 2][myh], a3 = alpha_sh[wid][j + 3][myh];
            const ushort2 u0 = *(const ushort2*)&z16[(size_t)s0 * CH + lane * 2];
            const ushort2 u1 = *(const ushort2*)&z16[(size_t)s1 * CH + lane * 2];
            const ushort2 u2 = *(const ushort2*)&z16[(size_t)s2 * CH + lane * 2];
            const ushort2 u3 = *(const ushort2*)&z16[(size_t)s3 * CH + lane * 2];
            acc.x = fmaf(a0, bf16_to_f(u0.x), acc.x); acc.y = fmaf(a0, bf16_to_f(u0.y), acc.y);
            acc.x = fmaf(a1, bf16_to_f(u1.x), acc.x); acc.y = fmaf(a1, bf16_to_f(u1.y), acc.y);
            acc.x = fmaf(a2, bf16_to_f(u2.x), acc.x); acc.y = fmaf(a2, bf16_to_f(u2.y), acc.y);
            acc.x = fmaf(a3, bf16_to_f(u3.x), acc.x); acc.y = fmaf(a3, bf16_to_f(u3.y), acc.y);
        }
        for (; j < deg; ++j) {
            const int s0 = es_sh[wid][j];
            const float a0 = alpha_sh[wid][j][myh];
            const ushort2 u0 = *(const ushort2*)&z16[(size_t)s0 * CH + lane * 2];
            acc.x = fmaf(a0, bf16_to_f(u0.x), acc.x); acc.y = fmaf(a0, bf16_to_f(u0.y), acc.y);
        }
    } else {
        // ---- fallback: chunked path (block-uniform barriers) ----
        const int nch = (maxdeg + 127) >> 7;
        for (int i = beg + lane; i < end; i += 64) {
            const int s = es[i];
            if (H == 4) {
                const float4 sv = *(const float4*)&s_src[(size_t)s * 4];
                const float svv[4] = {sv.x, sv.y, sv.z, sv.w};
                #pragma unroll
                for (int h = 0; h < 4; ++h) {
                    float v = svv[h] + sdv[h];
                    v = v > 0.f ? v : 0.01f * v;
                    const float mn = fmaxf(m[h], v);
                    ssum[h] = ssum[h] * __expf(m[h] - mn) + __expf(v - mn);
                    m[h] = mn;
                }
            } else {
                float v = s_src[s] + sdv[0];
                v = v > 0.f ? v : 0.01f * v;
                const float mn = fmaxf(m[0], v);
                ssum[0] = ssum[0] * __expf(m[0] - mn) + __expf(v - mn);
                m[0] = mn;
            }
        }
        #pragma unroll
        for (int h = 0; h < H; ++h) {
            float mg = m[h];
            #pragma unroll
            for (int off = 1; off < 64; off <<= 1)
                mg = fmaxf(mg, __shfl_xor(mg, off, 64));
            float sg = ssum[h] * __expf(m[h] - mg);
            #pragma unroll
            for (int off = 1; off < 64; off <<= 1)
                sg += __shfl_xor(sg, off, 64);
            m[h] = mg;
            inv[h] = 1.0f / fmaxf(sg, 1e-9f);
        }
        for (int k = 0; k < nch; ++k) {
            const int base = beg + k * 128;
            int cnt = end - base;
            cnt = cnt < 0 ? 0 : (cnt > 128 ? 128 : cnt);
            for (int idx = lane; idx < cnt; idx += 64) {
                const int s = es[base + idx];
                es_sh[wid][idx] = s;
                if (H == 4) {
                    const float4 sv = *(const float4*)&s_src[(size_t)s * 4];
                    const float svv[4] = {sv.x, sv.y, sv.z, sv.w};
                    float a4[4];
                    #pragma unroll
                    for (int h = 0; h < 4; ++h) {
                        float v = svv[h] + sdv[h];
                        v = v > 0.f ? v : 0.01f * v;
                        a4[h] = __expf(v - m[h]) * inv[h];
                    }
                    *(float4*)&alpha_sh[wid][idx][0] = make_float4(a4[0], a4[1], a4[2], a4[3]);
                } else {
                    float v = s_src[s] + sdv[0];
                    v = v > 0.f ? v : 0.01f * v;
                    alpha_sh[wid][idx][0] = __expf(v - m[0]) * inv[0];
                }
            }
            __syncthreads();
            for (int j = 0; j < cnt; ++j) {
                const int s0 = es_sh[wid][j];
                const float a0 = alpha_sh[wid][j][myh];
                const ushort2 u0 = *(const ushort2*)&z16[(size_t)s0 * CH + lane * 2];
                acc.x = fmaf(a0, bf16_to_f(u0.x), acc.x);
                acc.y = fmaf(a0, bf16_to_f(u0.y), acc.y);
            }
            __syncthreads();
        }
    }

    if (ELU) {
        acc.x = acc.x > 0.f ? acc.x : expm1f(acc.x);
        acc.y = acc.y > 0.f ? acc.y : expm1f(acc.y);
    }
    *(float2*)&out[(size_t)n * CH + lane * 2] = acc;
}

// ---------------- host ----------------
extern "C" void kernel_launch(void* const* d_in, const int* in_sizes, int n_in,
                              void* d_out, int out_size, void* d_ws, size_t ws_size,
                              hipStream_t stream)
{
    const float* h   = (const float*)d_in[0];
    const float* W1  = (const float*)d_in[1];
    const float* a1  = (const float*)d_in[2];
    const float* W2  = (const float*)d_in[3];
    const float* a2  = (const float*)d_in[4];
    const int*   src = (const int*)d_in[5];
    const int*   dst = (const int*)d_in[6];
    float* out = (float*)d_out;

    char* ws = (char*)d_ws;
    unsigned short* Bthi1 = (unsigned short*)(ws + 0);          // 192KB
    unsigned short* Btlo1 = (unsigned short*)(ws + 196608);     // 192KB
    unsigned short* Bthi2 = (unsigned short*)(ws + 393216);     // 32KB
    unsigned short* Btlo2 = (unsigned short*)(ws + 425984);     // 32KB
    float* ss      = (float*)(ws + 458752);                     // 800KB
    float* sd      = (float*)(ws + 1258752);                    // 800KB
    int*   counts  = (int*)  (ws + 2058752);                    // 200KB
    int*   exc     = (int*)  (ws + 2258752);                    // 200KB
    int*   bsum    = (int*)  (ws + 2458752);                    // 1KB
    int*   bexc    = (int*)  (ws + 2459776);                    // 1KB
    int*   offsets = (int*)  (ws + 2460800);                    // 200KB+4
    int*   cursor  = (int*)  (ws + 2661056);                    // 200KB
    int*   es      = (int*)  (ws + 2861056);                    // 3.2MB
    unsigned short* z16 = (unsigned short*)(ws + 6061056);      // 12.8MB
    float* h1      = (float*)(ws + 18861056);                   // 25.6MB

    const int EB = 256;
    const int egrid = (NE + EB - 1) / EB;
    const int sgrid = NN / 4;

    // --- CSR build (shared by both layers) ---
    zero_cc<<<NBLK, 256, 0, stream>>>(counts, cursor);
    count_k<<<egrid, EB, 0, stream>>>(dst, counts);
    scan1<<<NBLK, 256, 0, stream>>>(counts, exc, bsum);
    scan2<<<1, 256, 0, stream>>>(bsum, bexc);
    scan3<<<NBLK, 256, 0, stream>>>(exc, bexc, offsets);
    scatter_es<<<egrid, EB, 0, stream>>>(src, dst, offsets, cursor, es);

    // --- weight prep (split bf16, tiled+swizzled) ---
    prep_b1<<<(CH * IND + 255) / 256, 256, 0, stream>>>(W1, Bthi1, Btlo1);
    prep_b2<<<(CH * CH + 255) / 256, 256, 0, stream>>>(W2, Bthi2, Btlo2);

    // --- layer 1: GEMM (fused z16 + scores) -> aggregate ---
    gemm_fused<4><<<MBLKS, 256, 0, stream>>>(h, Bthi1, Btlo1, a1, z16, ss, sd, IND);
    fused_agg<4, true><<<sgrid, 256, 0, stream>>>(offsets, es, ss, sd, z16, h1);

    // --- layer 2: GEMM (fused z16 + scores) -> aggregate ---
    gemm_fused<1><<<MBLKS, 256, 0, stream>>>(h1, Bthi2, Btlo2, a2, z16, ss, sd, CH);
    fused_agg<1, false><<<sgrid, 256, 0, stream>>>(offsets, es, ss, sd, z16, out);
}